// Round 16
// baseline (46.275 us; speedup 1.0000x reference)
//
#include <hip/hip_runtime.h>
#include <hip/hip_bf16.h>

typedef float f32x4 __attribute__((ext_vector_type(4)));
typedef short bf16x8 __attribute__((ext_vector_type(8)));
typedef _Float16 f16x8 __attribute__((ext_vector_type(8)));

#define MFMA16 __builtin_amdgcn_mfma_f32_16x16x32_bf16

static constexpr int KDIM = 1700;
static constexpr int NKT2 = 56;         // padded k-tiles: 54 real (53 ragged) + 2 zero
static constexpr float BETA = 0.9f;
static constexpr float THRESH = 1.0f;

// fp32 -> bf16 hi + bf16 lo (residual), via HW cvt
__device__ __forceinline__ void split_bf(float f, short& hi, short& lo) {
    __hip_bfloat16 h = __float2bfloat16(f);
    float r = f - __bfloat162float(h);          // exact in fp32
    __hip_bfloat16 l = __float2bfloat16(r);
    hi = (short)__builtin_bit_cast(unsigned short, h);
    lo = (short)__builtin_bit_cast(unsigned short, l);
}

__device__ __forceinline__ void split8(f32x4 a, f32x4 b, bf16x8& hi, bf16x8& lo) {
    #pragma unroll
    for (int i = 0; i < 4; ++i) { short h, l; split_bf(a[i], h, l); hi[i] = h; lo[i] = l; }
    #pragma unroll
    for (int i = 0; i < 4; ++i) { short h, l; split_bf(b[i], h, l); hi[4 + i] = h; lo[4 + i] = l; }
}

// W1 [64][1700] f32 -> two bf16 planes in MFMA-B-fragment order, 56 k-tiles
// (k >= 1700 zero-padded).
__global__ void w1_relayout(const float* __restrict__ W1,
                            short* __restrict__ WTh, short* __restrict__ WTl) {
    const int g    = blockIdx.x * 256 + threadIdx.x;   // 0 .. 56*256-1
    const int kt   = g >> 8;
    const int nt   = (g >> 6) & 3;
    const int lane = g & 63;
    const int n    = nt * 16 + (lane & 15);
    const int kb   = kt * 32 + (lane >> 4) * 8;
    bf16x8 vh, vl;
    #pragma unroll
    for (int i = 0; i < 8; ++i) {
        const int k = kb + i;
        const float v = (k < KDIM) ? W1[n * KDIM + k] : 0.f;
        short h, l; split_bf(v, h, l);
        vh[i] = h; vl[i] = l;
    }
    *(bf16x8*)(WTh + (size_t)g * 8) = vh;
    *(bf16x8*)(WTl + (size_t)g * 8) = vl;
}

__device__ __forceinline__ void gll16(const short* src, const short* lds_dst) {
    __builtin_amdgcn_global_load_lds(
        (const __attribute__((address_space(1))) unsigned int*)src,
        (__attribute__((address_space(3))) unsigned int*)lds_dst, 16, 0, 0);
}

// ---------------- kernel A: partial cur1 over one K-eighth (r12, verified) ---
// Grid = 8 eighths x 64 row-groups. Block = 512 thr = 8 waves, 256 rows/block.
// W eighth (7 tiles, 56KB) staged into LDS ONCE; K-loop has ONLY x in the
// vmcnt domain (3-deep asm ring, counted waits). vs r12: fp16 partials +
// coalesced stores via per-wave LDS transpose. launch_bounds kept at (512,1):
// the 128-VGPR cap of (512,4) forces spills of async-asm load destinations
// (r15 crash suspect) — the asm x-ring REQUIRES the full 256-VGPR budget.
__global__ __launch_bounds__(512, 1) void gemmq(
    const float* __restrict__ x,
    const short* __restrict__ WTh, const short* __restrict__ WTl,
    _Float16* __restrict__ pcur)
{
    __shared__ __align__(16) short ldsW[7 * 4096];  // 56KB: [tile][hi 2048 | lo 2048]
    const int tid  = threadIdx.x;
    const int wid  = tid >> 6;                      // 0..7
    const int lane = tid & 63;
    const int l15  = lane & 15;
    const int g4   = lane >> 4;
    const int kg   = g4 * 8;
    const int e    = blockIdx.x & 7;                // k-eighth
    const int rgrp = blockIdx.x >> 3;               // 0..63
    const int rowBase = rgrp * 256 + wid * 32;
    const int tb   = e * 7;                         // first k-tile of this eighth

    // ---- stage W eighth: 56 x 1KB chunks, wave w stages chunks 7w..7w+6 -----
    #pragma unroll
    for (int c = 0; c < 7; ++c) {
        const int chunk = wid * 7 + c;
        const int tile  = chunk >> 3;
        const int q     = chunk & 7;
        const short* src = (q < 4)
            ? WTh + (size_t)(tb + tile) * 2048 + q * 512
            : WTl + (size_t)(tb + tile) * 2048 + (q - 4) * 512;
        short* dst = ldsW + tile * 4096 + ((q < 4) ? q * 512 : 2048 + (q - 4) * 512);
        gll16(src + lane * 8, dst);
    }

    const float* xr0 = x + (size_t)(rowBase + l15) * KDIM;
    const float* xr1 = xr0 + (size_t)16 * KDIM;

    struct XB { f32x4 a0, a1, b0, b1; };
    auto xload = [&](int t, XB& xb) {
        const int k1  = t * 32 + kg;
        const int kc1 = (k1 <= 1696) ? k1 : 1664;
        const int kc2 = (k1 + 4 <= 1696) ? k1 + 4 : 1664;
        const float* p0 = xr0 + kc1;
        const float* p1 = xr0 + kc2;
        const float* p2 = xr1 + kc1;
        const float* p3 = xr1 + kc2;
        asm volatile("global_load_dwordx4 %0, %1, off" : "=v"(xb.a0) : "v"(p0));
        asm volatile("global_load_dwordx4 %0, %1, off" : "=v"(xb.a1) : "v"(p1));
        asm volatile("global_load_dwordx4 %0, %1, off" : "=v"(xb.b0) : "v"(p2));
        asm volatile("global_load_dwordx4 %0, %1, off" : "=v"(xb.b1) : "v"(p3));
    };

    XB x0, x1, x2;
    xload(tb + 0, x0);
    xload(tb + 1, x1);
    xload(tb + 2, x2);

    asm volatile("s_waitcnt vmcnt(12)" ::: "memory");   // W stage done
    __builtin_amdgcn_sched_barrier(0);
    __builtin_amdgcn_s_barrier();        // raw barrier: x ring keeps flying

    f32x4 acc[2][4] = {};

#define QSTEP(I, XC, WAITN)                                                    \
    {                                                                          \
        asm volatile("s_waitcnt vmcnt(" #WAITN ")" ::: "memory");              \
        __builtin_amdgcn_sched_barrier(0);                                     \
        const short* rb = ldsW + (I) * 4096;                                   \
        bf16x8 WC[8];                                                          \
        _Pragma("unroll")                                                      \
        for (int q = 0; q < 8; ++q)                                            \
            WC[q] = *(const bf16x8*)(rb + q * 512 + lane * 8);                 \
        bf16x8 ah0, al0, ah1, al1;                                             \
        split8(XC.a0, XC.a1, ah0, al0);                                        \
        split8(XC.b0, XC.b1, ah1, al1);                                        \
        if constexpr ((I) + 3 < 7) xload(tb + (I) + 3, XC);                    \
        asm volatile("s_waitcnt lgkmcnt(0)" ::: "memory");                     \
        __builtin_amdgcn_sched_barrier(0);                                     \
        _Pragma("unroll")                                                      \
        for (int nt = 0; nt < 4; ++nt) {                                       \
            acc[0][nt] = MFMA16(ah0, WC[nt],     acc[0][nt], 0, 0, 0);         \
            acc[0][nt] = MFMA16(al0, WC[nt],     acc[0][nt], 0, 0, 0);         \
            acc[0][nt] = MFMA16(ah0, WC[4 + nt], acc[0][nt], 0, 0, 0);         \
            acc[1][nt] = MFMA16(ah1, WC[nt],     acc[1][nt], 0, 0, 0);         \
            acc[1][nt] = MFMA16(al1, WC[nt],     acc[1][nt], 0, 0, 0);         \
            acc[1][nt] = MFMA16(ah1, WC[4 + nt], acc[1][nt], 0, 0, 0);         \
        }                                                                      \
    }

    QSTEP(0, x0, 8)
    QSTEP(1, x1, 8)
    QSTEP(2, x2, 8)
    QSTEP(3, x0, 8)
    QSTEP(4, x1, 8)
    QSTEP(5, x2, 4)
    QSTEP(6, x0, 0)
#undef QSTEP

    // ---- fp16 partial store, coalesced via per-wave LDS transpose -----------
    __syncthreads();                                // all waves done with ldsW
    _Float16* ldsH = (_Float16*)ldsW;               // [wave][32 rows][72 half]
    _Float16* myH  = ldsH + wid * 2304;
    #pragma unroll
    for (int mt = 0; mt < 2; ++mt)
        #pragma unroll
        for (int nt = 0; nt < 4; ++nt)
            #pragma unroll
            for (int j = 0; j < 4; ++j)
                myH[(mt * 16 + g4 * 4 + j) * 72 + nt * 16 + l15] =
                    (_Float16)acc[mt][nt][j];
    // wave-local write->read; compiler inserts lgkmcnt. 1KB-contiguous stores:
    _Float16* pq = pcur + ((size_t)e << 20) + (size_t)rowBase * 64;  // e*16384*64
    #pragma unroll
    for (int p = 0; p < 4; ++p) {
        const int row = p * 8 + (lane >> 3);
        const int seg = lane & 7;
        f16x8 v = *(const f16x8*)&myH[row * 72 + seg * 8];
        *(f16x8*)(pq + row * 64 + seg * 8) = v;
    }
}

// ---------------- kernel B: sum 8 fp16 partials + b1, LIF recurrence ---------
__global__ __launch_bounds__(256, 2) void recur(
    const _Float16* __restrict__ pcur, const float* __restrict__ b1,
    const float* __restrict__ W2, const float* __restrict__ b2,
    const float* __restrict__ W3, const float* __restrict__ b3,
    const int* __restrict__ nsp, float* __restrict__ out)
{
    const int tid = threadIdx.x;
    const int wid = tid >> 6;
    const int lane = tid & 63;
    const int l15 = lane & 15;
    const int g4  = lane >> 4;
    const int kg  = g4 * 8;
    const int row = blockIdx.x * 64 + wid * 16 + l15;

    float c1[2][8], c1m1[2][8];
    #pragma unroll
    for (int kt = 0; kt < 2; ++kt) {
        float s[8];
        #pragma unroll
        for (int i = 0; i < 8; ++i) s[i] = b1[kt * 32 + kg + i];
        #pragma unroll
        for (int e = 0; e < 8; ++e) {
            f16x8 v = *(const f16x8*)(pcur + ((size_t)e << 20)
                                      + (size_t)row * 64 + kt * 32 + kg);
            #pragma unroll
            for (int i = 0; i < 8; ++i) s[i] += (float)v[i];
        }
        #pragma unroll
        for (int i = 0; i < 8; ++i) {
            c1[kt][i] = s[i];
            c1m1[kt][i] = s[i] - THRESH;
        }
    }

    bf16x8 W2hf[2][2], W2lf[2][2];
    #pragma unroll
    for (int rt = 0; rt < 2; ++rt)
        #pragma unroll
        for (int kt = 0; kt < 2; ++kt) {
            const float* wp = W2 + (rt * 16 + l15) * 64 + kt * 32 + kg;
            split8(*(const f32x4*)wp, *(const f32x4*)(wp + 4), W2hf[rt][kt], W2lf[rt][kt]);
        }

    float b2v[2][4], b2m1[2][4], w3a[2][4], w3b[2][4];
    #pragma unroll
    for (int nt = 0; nt < 2; ++nt)
        #pragma unroll
        for (int j = 0; j < 4; ++j) {
            const int o = nt * 16 + g4 * 4 + j;
            b2v[nt][j]  = b2[o];
            b2m1[nt][j] = b2[o] - THRESH;
            w3a[nt][j] = W3[o];
            w3b[nt][j] = W3[32 + o];
        }

    float m1[2][8] = {};
    float m2[2][4] = {};
    const int ns = nsp[0];
    for (int s = 0; s < ns; ++s) {
        bf16x8 mh[2], ml[2];
        #pragma unroll
        for (int kt = 0; kt < 2; ++kt)
            #pragma unroll
            for (int i = 0; i < 8; ++i) {
                float m = m1[kt][i];
                m = __builtin_fmaf(BETA, m, (m > THRESH) ? c1m1[kt][i] : c1[kt][i]);
                m1[kt][i] = m;
                short h, l; split_bf(m, h, l);
                mh[kt][i] = h; ml[kt][i] = l;
            }
        f32x4 a2[2][2] = {};
        #pragma unroll
        for (int rt = 0; rt < 2; ++rt)
            #pragma unroll
            for (int kt = 0; kt < 2; ++kt) {
                a2[rt][kt] = MFMA16(W2hf[rt][kt], mh[kt], a2[rt][kt], 0, 0, 0);
                a2[rt][kt] = MFMA16(W2lf[rt][kt], mh[kt], a2[rt][kt], 0, 0, 0);
                a2[rt][kt] = MFMA16(W2hf[rt][kt], ml[kt], a2[rt][kt], 0, 0, 0);
            }
        #pragma unroll
        for (int nt = 0; nt < 2; ++nt) {
            f32x4 c2 = a2[nt][0] + a2[nt][1];
            #pragma unroll
            for (int j = 0; j < 4; ++j) {
                float m = m2[nt][j];
                m2[nt][j] = __builtin_fmaf(
                    BETA, m, c2[j] + ((m > THRESH) ? b2m1[nt][j] : b2v[nt][j]));
            }
        }
    }

    float p0 = 0.f, p1 = 0.f;
    #pragma unroll
    for (int nt = 0; nt < 2; ++nt)
        #pragma unroll
        for (int j = 0; j < 4; ++j) {
            p0 = __builtin_fmaf(m2[nt][j], w3a[nt][j], p0);
            p1 = __builtin_fmaf(m2[nt][j], w3b[nt][j], p1);
        }
    p0 += __shfl_xor(p0, 16); p0 += __shfl_xor(p0, 32);
    p1 += __shfl_xor(p1, 16); p1 += __shfl_xor(p1, 32);
    if (lane < 16) {
        out[(size_t)row * 2 + 0] = p0 + b3[0];
        out[(size_t)row * 2 + 1] = p1 + b3[1];
    }
}

extern "C" void kernel_launch(void* const* d_in, const int* in_sizes, int n_in,
                              void* d_out, int out_size, void* d_ws, size_t ws_size,
                              hipStream_t stream) {
    const float* x  = (const float*)d_in[0];
    const float* W1 = (const float*)d_in[1];
    const float* b1 = (const float*)d_in[2];
    const float* W2 = (const float*)d_in[3];
    const float* b2 = (const float*)d_in[4];
    const float* W3 = (const float*)d_in[5];
    const float* b3 = (const float*)d_in[6];
    const int*   ns = (const int*)d_in[7];
    float* o = (float*)d_out;

    const int B = in_sizes[0] / KDIM;              // 16384
    short* WTh  = (short*)d_ws;                    // [56][2048] bf16 hi (229 KB)
    short* WTl  = WTh + (size_t)NKT2 * 2048;       // [56][2048] bf16 lo
    _Float16* pcur = (_Float16*)((char*)d_ws + (2 << 20)); // [8][16384][64] f16 = 16.8MB

    w1_relayout<<<NKT2, 256, 0, stream>>>(W1, WTh, WTl);
    gemmq<<<8 * (B / 256), 512, 0, stream>>>(x, WTh, WTl, pcur);
    recur<<<B / 64, 256, 0, stream>>>(pcur, b1, W2, b2, W3, b3, ns, o);
}

// Round 17
// 43.937 us; speedup vs baseline: 1.0532x; 1.0532x over previous
//
#include <hip/hip_runtime.h>
#include <hip/hip_bf16.h>

typedef float f32x4 __attribute__((ext_vector_type(4)));
typedef short bf16x8 __attribute__((ext_vector_type(8)));

#define MFMA16 __builtin_amdgcn_mfma_f32_16x16x32_bf16

static constexpr int KDIM = 1700;
static constexpr int NKT2 = 56;         // padded k-tiles: 54 real (53 ragged) + 2 zero
static constexpr float BETA = 0.9f;
static constexpr float THRESH = 1.0f;

// fp32 -> bf16 hi + bf16 lo (residual), via HW cvt
__device__ __forceinline__ void split_bf(float f, short& hi, short& lo) {
    __hip_bfloat16 h = __float2bfloat16(f);
    float r = f - __bfloat162float(h);          // exact in fp32
    __hip_bfloat16 l = __float2bfloat16(r);
    hi = (short)__builtin_bit_cast(unsigned short, h);
    lo = (short)__builtin_bit_cast(unsigned short, l);
}

__device__ __forceinline__ void split8(f32x4 a, f32x4 b, bf16x8& hi, bf16x8& lo) {
    #pragma unroll
    for (int i = 0; i < 4; ++i) { short h, l; split_bf(a[i], h, l); hi[i] = h; lo[i] = l; }
    #pragma unroll
    for (int i = 0; i < 4; ++i) { short h, l; split_bf(b[i], h, l); hi[4 + i] = h; lo[4 + i] = l; }
}

// W1 [64][1700] f32 -> two bf16 planes in MFMA-B-fragment order, 56 k-tiles
// (k >= 1700 zero-padded):
// WT[((kt*4 + nt)*64 + lane)*8 + i] = W1[nt*16 + (lane&15)][kt*32 + (lane>>4)*8 + i]
__global__ void w1_relayout(const float* __restrict__ W1,
                            short* __restrict__ WTh, short* __restrict__ WTl) {
    const int g    = blockIdx.x * 256 + threadIdx.x;   // 0 .. 56*256-1
    const int kt   = g >> 8;
    const int nt   = (g >> 6) & 3;
    const int lane = g & 63;
    const int n    = nt * 16 + (lane & 15);
    const int kb   = kt * 32 + (lane >> 4) * 8;
    bf16x8 vh, vl;
    #pragma unroll
    for (int i = 0; i < 8; ++i) {
        const int k = kb + i;
        const float v = (k < KDIM) ? W1[n * KDIM + k] : 0.f;
        short h, l; split_bf(v, h, l);
        vh[i] = h; vl[i] = l;
    }
    *(bf16x8*)(WTh + (size_t)g * 8) = vh;
    *(bf16x8*)(WTl + (size_t)g * 8) = vl;
}

__device__ __forceinline__ void gll16(const short* src, const short* lds_dst) {
    __builtin_amdgcn_global_load_lds(
        (const __attribute__((address_space(1))) unsigned int*)src,
        (__attribute__((address_space(3))) unsigned int*)lds_dst, 16, 0, 0);
}

// ---------------- fused kernel: cur1 GEMM (LDS-staged W) + LIF recurrence ----
// 256 thr = 4 waves, 32 rows/block, K-split-4: wave w owns 14 k-tiles.
// W streams HBM/L2 -> wave-private LDS dbuf (global_load_lds, vmcnt);
// x streams via inline-asm global_load_dwordx4, 3-step register ring.
// One counted s_waitcnt vmcnt(N) per step (issue order makes the count exact);
// x loads keep ~3 steps of latency slack and are never drained early.
__global__ __launch_bounds__(256, 2) void snn_fused(
    const float* __restrict__ x,
    const short* __restrict__ WTh, const short* __restrict__ WTl,
    const float* __restrict__ b1, const float* __restrict__ W2,
    const float* __restrict__ b2, const float* __restrict__ W3,
    const float* __restrict__ b3, const int* __restrict__ nsp,
    float* __restrict__ out)
{
    __shared__ __align__(16) char smemraw[65536];   // ldsW (64KB) / red (aliased)
    short* ldsW = (short*)smemraw;
    float (*red)[32][68] = (float (*)[32][68])smemraw;

    const int tid = threadIdx.x;
    const int wid = tid >> 6;
    const int lane = tid & 63;
    const int l15 = lane & 15;
    const int g4  = lane >> 4;
    const int kg  = g4 * 8;
    const int rowBase = blockIdx.x * 32;
    const int t0  = wid * 14;

    const float* xr0 = x + (size_t)(rowBase + l15) * KDIM;
    const float* xr1 = xr0 + (size_t)16 * KDIM;
    const short* pWh = WTh + (size_t)t0 * 2048 + lane * 8;  // per-lane W src
    const short* pWl = WTl + (size_t)t0 * 2048 + lane * 8;
    short* myLds = ldsW + wid * 8192;              // 16KB/wave (2 x 8KB bufs)

    struct XB { f32x4 a0, a1, b0, b1; };
    // x fragment load via inline asm (pinned issue point; NO auto-waitcnt —
    // consumption is guarded by the explicit counted vmcnt below).
    // Addresses clamped in-row for k >= 1700 (matching W entries are zero).
    auto xload = [&](int t, XB& xb) {
        const int k1 = t * 32 + kg;
        const int kc1 = (k1 <= 1696) ? k1 : 1664;
        const int kc2 = (k1 + 4 <= 1696) ? k1 + 4 : 1664;
        const float* p0 = xr0 + kc1;
        const float* p1 = xr0 + kc2;
        const float* p2 = xr1 + kc1;
        const float* p3 = xr1 + kc2;
        asm volatile("global_load_dwordx4 %0, %1, off" : "=v"(xb.a0) : "v"(p0));
        asm volatile("global_load_dwordx4 %0, %1, off" : "=v"(xb.a1) : "v"(p1));
        asm volatile("global_load_dwordx4 %0, %1, off" : "=v"(xb.b0) : "v"(p2));
        asm volatile("global_load_dwordx4 %0, %1, off" : "=v"(xb.b1) : "v"(p3));
    };
    // stage tile (t0+i) into my wave's LDS buffer `buf` (8 x 1KB, vmcnt-tracked)
    auto stageW = [&](int i, int buf) {
        short* dstb = myLds + buf * 4096;
        #pragma unroll
        for (int q = 0; q < 4; ++q) {
            gll16(pWh + (size_t)i * 2048 + q * 512, dstb + q * 512);
            gll16(pWl + (size_t)i * 2048 + q * 512, dstb + 2048 + q * 512);
        }
    };

    f32x4 acc[2][4] = {};
    XB x0, x1, x2;

    // prologue issue order: W0, x0, x1, W1, x2  (28 outstanding)
    stageW(0, 0);
    xload(t0 + 0, x0);
    xload(t0 + 1, x1);
    stageW(1, 1);
    xload(t0 + 2, x2);

    // step I: wait vmcnt(WAITN) completes W(I)+x(I), keeps newer loads flying.
#define GSTEP(I, XC, WAITN)                                                    \
    {                                                                          \
        asm volatile("s_waitcnt vmcnt(" #WAITN ")" ::: "memory");              \
        __builtin_amdgcn_sched_barrier(0);                                     \
        const short* rb = myLds + ((I) & 1) * 4096;                            \
        bf16x8 WC[8];                                                          \
        _Pragma("unroll")                                                      \
        for (int q = 0; q < 8; ++q)                                            \
            WC[q] = *(const bf16x8*)(rb + q * 512 + lane * 8);                 \
        bf16x8 ah0, al0, ah1, al1;                                             \
        split8(XC.a0, XC.a1, ah0, al0);                                        \
        split8(XC.b0, XC.b1, ah1, al1);                                        \
        asm volatile("s_waitcnt lgkmcnt(0)" ::: "memory");                     \
        __builtin_amdgcn_sched_barrier(0);                                     \
        if constexpr ((I) + 2 < 14) stageW((I) + 2, (I) & 1);                  \
        if constexpr ((I) + 3 < 14) xload(t0 + (I) + 3, XC);                   \
        __builtin_amdgcn_sched_barrier(0);                                     \
        _Pragma("unroll")                                                      \
        for (int nt = 0; nt < 4; ++nt) {                                       \
            acc[0][nt] = MFMA16(ah0, WC[nt],     acc[0][nt], 0, 0, 0);         \
            acc[0][nt] = MFMA16(al0, WC[nt],     acc[0][nt], 0, 0, 0);         \
            acc[0][nt] = MFMA16(ah0, WC[4 + nt], acc[0][nt], 0, 0, 0);         \
            acc[1][nt] = MFMA16(ah1, WC[nt],     acc[1][nt], 0, 0, 0);         \
            acc[1][nt] = MFMA16(al1, WC[nt],     acc[1][nt], 0, 0, 0);         \
            acc[1][nt] = MFMA16(ah1, WC[4 + nt], acc[1][nt], 0, 0, 0);         \
        }                                                                      \
    }

    GSTEP(0,  x0, 16)
    GSTEP(1,  x1, 16)
    GSTEP(2,  x2, 16)
    GSTEP(3,  x0, 16)
    GSTEP(4,  x1, 16)
    GSTEP(5,  x2, 16)
    GSTEP(6,  x0, 16)
    GSTEP(7,  x1, 16)
    GSTEP(8,  x2, 16)
    GSTEP(9,  x0, 16)
    GSTEP(10, x1, 16)
    GSTEP(11, x2, 16)
    GSTEP(12, x0, 12)
    GSTEP(13, x1, 0)
#undef GSTEP

    // ldsW regions of different waves alias red[] -> sync BEFORE overwriting
    __syncthreads();

    // partials -> LDS (C-layout: row = mt*16 + g4*4 + j, col = nt*16 + l15)
    #pragma unroll
    for (int mt = 0; mt < 2; ++mt)
        #pragma unroll
        for (int nt = 0; nt < 4; ++nt)
            #pragma unroll
            for (int j = 0; j < 4; ++j)
                red[wid][mt * 16 + g4 * 4 + j][nt * 16 + l15] = acc[mt][nt][j];
    __syncthreads();

    // reduce 4 k-partials + b1 into red[0] (disjoint (rr,seg) slots: race-free)
    {
        const int rr  = tid >> 3;
        const int seg = tid & 7;
        f32x4 s0 = *(const f32x4*)(b1 + seg * 8);
        f32x4 s1 = *(const f32x4*)(b1 + seg * 8 + 4);
        #pragma unroll
        for (int p = 0; p < 4; ++p) {
            s0 += *(const f32x4*)&red[p][rr][seg * 8];
            s1 += *(const f32x4*)&red[p][rr][seg * 8 + 4];
        }
        *(f32x4*)&red[0][rr][seg * 8]     = s0;
        *(f32x4*)&red[0][rr][seg * 8 + 4] = s1;
    }
    __syncthreads();
    if (wid >= 2) return;                     // waves 2,3 done (no barriers below)

    // ---------------- phase 2: 20-step LIF recurrence, all in registers ------
    const int lrow = wid * 16 + l15;

    float c1[2][8], c1m1[2][8];
    #pragma unroll
    for (int kt = 0; kt < 2; ++kt) {
        f32x4 u0 = *(const f32x4*)&red[0][lrow][kt * 32 + kg];
        f32x4 u1 = *(const f32x4*)&red[0][lrow][kt * 32 + kg + 4];
        #pragma unroll
        for (int i = 0; i < 4; ++i) {
            c1[kt][i] = u0[i];     c1[kt][4 + i] = u1[i];
            c1m1[kt][i] = u0[i] - THRESH; c1m1[kt][4 + i] = u1[i] - THRESH;
        }
    }

    bf16x8 W2hf[2][2], W2lf[2][2];
    #pragma unroll
    for (int rt = 0; rt < 2; ++rt)
        #pragma unroll
        for (int kt = 0; kt < 2; ++kt) {
            const float* wp = W2 + (rt * 16 + l15) * 64 + kt * 32 + kg;
            split8(*(const f32x4*)wp, *(const f32x4*)(wp + 4), W2hf[rt][kt], W2lf[rt][kt]);
        }

    float b2v[2][4], b2m1[2][4], w3a[2][4], w3b[2][4];
    #pragma unroll
    for (int nt = 0; nt < 2; ++nt)
        #pragma unroll
        for (int j = 0; j < 4; ++j) {
            const int o = nt * 16 + g4 * 4 + j;
            b2v[nt][j]  = b2[o];
            b2m1[nt][j] = b2[o] - THRESH;
            w3a[nt][j] = W3[o];
            w3b[nt][j] = W3[32 + o];
        }

    float m1[2][8] = {};
    float m2[2][4] = {};
    const int ns = nsp[0];
    for (int s = 0; s < ns; ++s) {
        bf16x8 mh[2], ml[2];
        #pragma unroll
        for (int kt = 0; kt < 2; ++kt)
            #pragma unroll
            for (int i = 0; i < 8; ++i) {
                float m = m1[kt][i];
                m = __builtin_fmaf(BETA, m, (m > THRESH) ? c1m1[kt][i] : c1[kt][i]);
                m1[kt][i] = m;
                short h, l; split_bf(m, h, l);
                mh[kt][i] = h; ml[kt][i] = l;
            }
        f32x4 a2[2][2] = {};
        #pragma unroll
        for (int rt = 0; rt < 2; ++rt)
            #pragma unroll
            for (int kt = 0; kt < 2; ++kt) {
                a2[rt][kt] = MFMA16(W2hf[rt][kt], mh[kt], a2[rt][kt], 0, 0, 0);
                a2[rt][kt] = MFMA16(W2lf[rt][kt], mh[kt], a2[rt][kt], 0, 0, 0);
                a2[rt][kt] = MFMA16(W2hf[rt][kt], ml[kt], a2[rt][kt], 0, 0, 0);
            }
        #pragma unroll
        for (int nt = 0; nt < 2; ++nt) {
            f32x4 c2 = a2[nt][0] + a2[nt][1];
            #pragma unroll
            for (int j = 0; j < 4; ++j) {
                float m = m2[nt][j];
                m2[nt][j] = __builtin_fmaf(
                    BETA, m, c2[j] + ((m > THRESH) ? b2m1[nt][j] : b2v[nt][j]));
            }
        }
    }

    float p0 = 0.f, p1 = 0.f;
    #pragma unroll
    for (int nt = 0; nt < 2; ++nt)
        #pragma unroll
        for (int j = 0; j < 4; ++j) {
            p0 = __builtin_fmaf(m2[nt][j], w3a[nt][j], p0);
            p1 = __builtin_fmaf(m2[nt][j], w3b[nt][j], p1);
        }
    p0 += __shfl_xor(p0, 16); p0 += __shfl_xor(p0, 32);
    p1 += __shfl_xor(p1, 16); p1 += __shfl_xor(p1, 32);
    if (lane < 16) {
        const size_t row = rowBase + lrow;
        out[row * 2 + 0] = p0 + b3[0];
        out[row * 2 + 1] = p1 + b3[1];
    }
}

extern "C" void kernel_launch(void* const* d_in, const int* in_sizes, int n_in,
                              void* d_out, int out_size, void* d_ws, size_t ws_size,
                              hipStream_t stream) {
    const float* x  = (const float*)d_in[0];
    const float* W1 = (const float*)d_in[1];
    const float* b1 = (const float*)d_in[2];
    const float* W2 = (const float*)d_in[3];
    const float* b2 = (const float*)d_in[4];
    const float* W3 = (const float*)d_in[5];
    const float* b3 = (const float*)d_in[6];
    const int*   ns = (const int*)d_in[7];
    float* o = (float*)d_out;

    const int B = in_sizes[0] / KDIM;              // 16384
    short* WTh  = (short*)d_ws;                    // [56][2048] bf16 hi
    short* WTl  = WTh + (size_t)NKT2 * 2048;       // [56][2048] bf16 lo

    w1_relayout<<<NKT2, 256, 0, stream>>>(W1, WTh, WTl);
    snn_fused<<<B / 32, 256, 0, stream>>>(x, WTh, WTl, b1, W2, b2, W3, b3, ns, o);
}

// Round 18
// 40.606 us; speedup vs baseline: 1.1396x; 1.0820x over previous
//
#include <hip/hip_runtime.h>
#include <hip/hip_bf16.h>

typedef float f32x4 __attribute__((ext_vector_type(4)));
typedef short bf16x8 __attribute__((ext_vector_type(8)));
typedef _Float16 f16x8 __attribute__((ext_vector_type(8)));

#define MFMA16  __builtin_amdgcn_mfma_f32_16x16x32_bf16
#define MFMA16F __builtin_amdgcn_mfma_f32_16x16x32_f16

static constexpr int KDIM = 1700;
static constexpr int NKT2 = 56;         // padded k-tiles: 54 real (53 ragged) + 2 zero
static constexpr float BETA = 0.9f;
static constexpr float THRESH = 1.0f;

// fp32 -> bf16 hi + bf16 lo (residual) — used in the recurrence (unchanged)
__device__ __forceinline__ void split_bf(float f, short& hi, short& lo) {
    __hip_bfloat16 h = __float2bfloat16(f);
    float r = f - __bfloat162float(h);          // exact in fp32
    __hip_bfloat16 l = __float2bfloat16(r);
    hi = (short)__builtin_bit_cast(unsigned short, h);
    lo = (short)__builtin_bit_cast(unsigned short, l);
}

__device__ __forceinline__ void split8(f32x4 a, f32x4 b, bf16x8& hi, bf16x8& lo) {
    #pragma unroll
    for (int i = 0; i < 4; ++i) { short h, l; split_bf(a[i], h, l); hi[i] = h; lo[i] = l; }
    #pragma unroll
    for (int i = 0; i < 4; ++i) { short h, l; split_bf(b[i], h, l); hi[4 + i] = h; lo[4 + i] = l; }
}

// fp32 -> fp16 hi + fp16 lo (residual): x representation error ~2^-22 relative
__device__ __forceinline__ void split8h(f32x4 a, f32x4 b, f16x8& hi, f16x8& lo) {
    #pragma unroll
    for (int i = 0; i < 4; ++i) {
        _Float16 h = (_Float16)a[i];
        hi[i] = h; lo[i] = (_Float16)(a[i] - (float)h);
    }
    #pragma unroll
    for (int i = 0; i < 4; ++i) {
        _Float16 h = (_Float16)b[i];
        hi[4 + i] = h; lo[4 + i] = (_Float16)(b[i] - (float)h);
    }
}

// W1 [64][1700] f32 -> ONE fp16 plane in MFMA-B-fragment order, 56 k-tiles
// (k >= 1700 zero-padded). fp16's 11-bit mantissa bounds cur1 error ~1.6e-4
// (std) — below the verified-passing r16 noise level.
// WT[((kt*4 + nt)*64 + lane)*8 + i] = fp16(W1[nt*16+(lane&15)][kt*32+(lane>>4)*8+i])
__global__ void w1_relayout(const float* __restrict__ W1, _Float16* __restrict__ WT) {
    const int g    = blockIdx.x * 256 + threadIdx.x;   // 0 .. 56*256-1
    const int kt   = g >> 8;
    const int nt   = (g >> 6) & 3;
    const int lane = g & 63;
    const int n    = nt * 16 + (lane & 15);
    const int kb   = kt * 32 + (lane >> 4) * 8;
    f16x8 v;
    #pragma unroll
    for (int i = 0; i < 8; ++i) {
        const int k = kb + i;
        v[i] = (k < KDIM) ? (_Float16)W1[n * KDIM + k] : (_Float16)0.f;
    }
    *(f16x8*)(WT + (size_t)g * 8) = v;
}

__device__ __forceinline__ void gll16(const void* src, const void* lds_dst) {
    __builtin_amdgcn_global_load_lds(
        (const __attribute__((address_space(1))) unsigned int*)src,
        (__attribute__((address_space(3))) unsigned int*)lds_dst, 16, 0, 0);
}

// ---------------- fused kernel: cur1 GEMM (LDS-staged fp16 W) + LIF ----------
// r11's verified counted-vmcnt pipeline with HALF the W stream: single fp16
// plane -> 4 gll16/tile (was 8), 16 MFMA/step (was 24). Per-step VMEM instr
// count 12 -> 8 — the isolated test of the instruction-count wall model.
// Queue ledger (validated method, r11): prologue W0[4],x0[4],x1[4],W1[4],x2[4]
// = 20 outstanding; steady wait 12 drains exactly x(I)+W(I); tail 8, 0.
__global__ __launch_bounds__(256, 2) void snn_fused(
    const float* __restrict__ x, const _Float16* __restrict__ WT,
    const float* __restrict__ b1, const float* __restrict__ W2,
    const float* __restrict__ b2, const float* __restrict__ W3,
    const float* __restrict__ b3, const int* __restrict__ nsp,
    float* __restrict__ out)
{
    __shared__ __align__(16) char smemraw[34816];   // ldsW 32KB (red aliased, 34.8KB)
    _Float16* ldsW = (_Float16*)smemraw;
    float (*red)[32][68] = (float (*)[32][68])smemraw;

    const int tid = threadIdx.x;
    const int wid = tid >> 6;
    const int lane = tid & 63;
    const int l15 = lane & 15;
    const int g4  = lane >> 4;
    const int kg  = g4 * 8;
    const int rowBase = blockIdx.x * 32;
    const int t0  = wid * 14;

    const float* xr0 = x + (size_t)(rowBase + l15) * KDIM;
    const float* xr1 = xr0 + (size_t)16 * KDIM;
    const _Float16* pW = WT + (size_t)t0 * 2048 + lane * 8;   // per-lane W src
    _Float16* myLds = ldsW + wid * 4096;            // 8KB/wave (2 x 4KB bufs)

    struct XB { f32x4 a0, a1, b0, b1; };
    // x fragment load via inline asm (pinned issue point; consumption guarded
    // by the explicit counted vmcnt). Clamped in-row for k >= 1700 (W zero).
    auto xload = [&](int t, XB& xb) {
        const int k1 = t * 32 + kg;
        const int kc1 = (k1 <= 1696) ? k1 : 1664;
        const int kc2 = (k1 + 4 <= 1696) ? k1 + 4 : 1664;
        const float* p0 = xr0 + kc1;
        const float* p1 = xr0 + kc2;
        const float* p2 = xr1 + kc1;
        const float* p3 = xr1 + kc2;
        asm volatile("global_load_dwordx4 %0, %1, off" : "=v"(xb.a0) : "v"(p0));
        asm volatile("global_load_dwordx4 %0, %1, off" : "=v"(xb.a1) : "v"(p1));
        asm volatile("global_load_dwordx4 %0, %1, off" : "=v"(xb.b0) : "v"(p2));
        asm volatile("global_load_dwordx4 %0, %1, off" : "=v"(xb.b1) : "v"(p3));
    };
    // stage tile (t0+i) into wave-private LDS buffer `buf` (4 x 1KB, vmcnt)
    auto stageW = [&](int i, int buf) {
        _Float16* dstb = myLds + buf * 2048;
        #pragma unroll
        for (int q = 0; q < 4; ++q)
            gll16(pW + (size_t)i * 2048 + q * 512, dstb + q * 512);
    };

    f32x4 acc[2][4] = {};
    XB x0, x1, x2;

    // prologue issue order: W0, x0, x1, W1, x2  (20 outstanding)
    stageW(0, 0);
    xload(t0 + 0, x0);
    xload(t0 + 1, x1);
    stageW(1, 1);
    xload(t0 + 2, x2);

    // step I: wait vmcnt(WAITN) completes W(I)+x(I), keeps newer loads flying.
    // HAZARD ORDER (r14 lesson): WC ds_reads of buffer I&1 complete (lgkmcnt 0)
    // BEFORE stageW(I+2) re-stages that same buffer.
#define GSTEP(I, XC, WAITN)                                                    \
    {                                                                          \
        asm volatile("s_waitcnt vmcnt(" #WAITN ")" ::: "memory");              \
        __builtin_amdgcn_sched_barrier(0);                                     \
        const _Float16* rb = myLds + ((I) & 1) * 2048;                         \
        f16x8 WC[4];                                                           \
        _Pragma("unroll")                                                      \
        for (int q = 0; q < 4; ++q)                                            \
            WC[q] = *(const f16x8*)(rb + q * 512 + lane * 8);                  \
        f16x8 ah0, al0, ah1, al1;                                              \
        split8h(XC.a0, XC.a1, ah0, al0);                                       \
        split8h(XC.b0, XC.b1, ah1, al1);                                       \
        asm volatile("s_waitcnt lgkmcnt(0)" ::: "memory");                     \
        __builtin_amdgcn_sched_barrier(0);                                     \
        if constexpr ((I) + 2 < 14) stageW((I) + 2, (I) & 1);                  \
        if constexpr ((I) + 3 < 14) xload(t0 + (I) + 3, XC);                   \
        __builtin_amdgcn_sched_barrier(0);                                     \
        _Pragma("unroll")                                                      \
        for (int nt = 0; nt < 4; ++nt) {                                       \
            acc[0][nt] = MFMA16F(ah0, WC[nt], acc[0][nt], 0, 0, 0);            \
            acc[0][nt] = MFMA16F(al0, WC[nt], acc[0][nt], 0, 0, 0);            \
            acc[1][nt] = MFMA16F(ah1, WC[nt], acc[1][nt], 0, 0, 0);            \
            acc[1][nt] = MFMA16F(al1, WC[nt], acc[1][nt], 0, 0, 0);            \
        }                                                                      \
    }

    GSTEP(0,  x0, 12)
    GSTEP(1,  x1, 12)
    GSTEP(2,  x2, 12)
    GSTEP(3,  x0, 12)
    GSTEP(4,  x1, 12)
    GSTEP(5,  x2, 12)
    GSTEP(6,  x0, 12)
    GSTEP(7,  x1, 12)
    GSTEP(8,  x2, 12)
    GSTEP(9,  x0, 12)
    GSTEP(10, x1, 12)
    GSTEP(11, x2, 12)
    GSTEP(12, x0, 8)
    GSTEP(13, x1, 0)
#undef GSTEP

    // ldsW regions of different waves alias red[] -> sync BEFORE overwriting
    __syncthreads();

    // partials -> LDS (C-layout: row = mt*16 + g4*4 + j, col = nt*16 + l15)
    #pragma unroll
    for (int mt = 0; mt < 2; ++mt)
        #pragma unroll
        for (int nt = 0; nt < 4; ++nt)
            #pragma unroll
            for (int j = 0; j < 4; ++j)
                red[wid][mt * 16 + g4 * 4 + j][nt * 16 + l15] = acc[mt][nt][j];
    __syncthreads();

    // reduce 4 k-partials + b1 into red[0] (disjoint (rr,seg) slots: race-free)
    {
        const int rr  = tid >> 3;
        const int seg = tid & 7;
        f32x4 s0 = *(const f32x4*)(b1 + seg * 8);
        f32x4 s1 = *(const f32x4*)(b1 + seg * 8 + 4);
        #pragma unroll
        for (int p = 0; p < 4; ++p) {
            s0 += *(const f32x4*)&red[p][rr][seg * 8];
            s1 += *(const f32x4*)&red[p][rr][seg * 8 + 4];
        }
        *(f32x4*)&red[0][rr][seg * 8]     = s0;
        *(f32x4*)&red[0][rr][seg * 8 + 4] = s1;
    }
    __syncthreads();
    if (wid >= 2) return;                     // waves 2,3 done (no barriers below)

    // ---------------- phase 2: 20-step LIF recurrence, all in registers ------
    const int lrow = wid * 16 + l15;

    float c1[2][8], c1m1[2][8];
    #pragma unroll
    for (int kt = 0; kt < 2; ++kt) {
        f32x4 u0 = *(const f32x4*)&red[0][lrow][kt * 32 + kg];
        f32x4 u1 = *(const f32x4*)&red[0][lrow][kt * 32 + kg + 4];
        #pragma unroll
        for (int i = 0; i < 4; ++i) {
            c1[kt][i] = u0[i];     c1[kt][4 + i] = u1[i];
            c1m1[kt][i] = u0[i] - THRESH; c1m1[kt][4 + i] = u1[i] - THRESH;
        }
    }

    bf16x8 W2hf[2][2], W2lf[2][2];
    #pragma unroll
    for (int rt = 0; rt < 2; ++rt)
        #pragma unroll
        for (int kt = 0; kt < 2; ++kt) {
            const float* wp = W2 + (rt * 16 + l15) * 64 + kt * 32 + kg;
            split8(*(const f32x4*)wp, *(const f32x4*)(wp + 4), W2hf[rt][kt], W2lf[rt][kt]);
        }

    float b2v[2][4], b2m1[2][4], w3a[2][4], w3b[2][4];
    #pragma unroll
    for (int nt = 0; nt < 2; ++nt)
        #pragma unroll
        for (int j = 0; j < 4; ++j) {
            const int o = nt * 16 + g4 * 4 + j;
            b2v[nt][j]  = b2[o];
            b2m1[nt][j] = b2[o] - THRESH;
            w3a[nt][j] = W3[o];
            w3b[nt][j] = W3[32 + o];
        }

    float m1[2][8] = {};
    float m2[2][4] = {};
    const int ns = nsp[0];
    for (int s = 0; s < ns; ++s) {
        bf16x8 mh[2], ml[2];
        #pragma unroll
        for (int kt = 0; kt < 2; ++kt)
            #pragma unroll
            for (int i = 0; i < 8; ++i) {
                float m = m1[kt][i];
                m = __builtin_fmaf(BETA, m, (m > THRESH) ? c1m1[kt][i] : c1[kt][i]);
                m1[kt][i] = m;
                short h, l; split_bf(m, h, l);
                mh[kt][i] = h; ml[kt][i] = l;
            }
        f32x4 a2[2][2] = {};
        #pragma unroll
        for (int rt = 0; rt < 2; ++rt)
            #pragma unroll
            for (int kt = 0; kt < 2; ++kt) {
                a2[rt][kt] = MFMA16(W2hf[rt][kt], mh[kt], a2[rt][kt], 0, 0, 0);
                a2[rt][kt] = MFMA16(W2lf[rt][kt], mh[kt], a2[rt][kt], 0, 0, 0);
                a2[rt][kt] = MFMA16(W2hf[rt][kt], ml[kt], a2[rt][kt], 0, 0, 0);
            }
        #pragma unroll
        for (int nt = 0; nt < 2; ++nt) {
            f32x4 c2 = a2[nt][0] + a2[nt][1];
            #pragma unroll
            for (int j = 0; j < 4; ++j) {
                float m = m2[nt][j];
                m2[nt][j] = __builtin_fmaf(
                    BETA, m, c2[j] + ((m > THRESH) ? b2m1[nt][j] : b2v[nt][j]));
            }
        }
    }

    float p0 = 0.f, p1 = 0.f;
    #pragma unroll
    for (int nt = 0; nt < 2; ++nt)
        #pragma unroll
        for (int j = 0; j < 4; ++j) {
            p0 = __builtin_fmaf(m2[nt][j], w3a[nt][j], p0);
            p1 = __builtin_fmaf(m2[nt][j], w3b[nt][j], p1);
        }
    p0 += __shfl_xor(p0, 16); p0 += __shfl_xor(p0, 32);
    p1 += __shfl_xor(p1, 16); p1 += __shfl_xor(p1, 32);
    if (lane < 16) {
        const size_t row = rowBase + lrow;
        out[row * 2 + 0] = p0 + b3[0];
        out[row * 2 + 1] = p1 + b3[1];
    }
}

extern "C" void kernel_launch(void* const* d_in, const int* in_sizes, int n_in,
                              void* d_out, int out_size, void* d_ws, size_t ws_size,
                              hipStream_t stream) {
    const float* x  = (const float*)d_in[0];
    const float* W1 = (const float*)d_in[1];
    const float* b1 = (const float*)d_in[2];
    const float* W2 = (const float*)d_in[3];
    const float* b2 = (const float*)d_in[4];
    const float* W3 = (const float*)d_in[5];
    const float* b3 = (const float*)d_in[6];
    const int*   ns = (const int*)d_in[7];
    float* o = (float*)d_out;

    const int B = in_sizes[0] / KDIM;              // 16384
    _Float16* WT = (_Float16*)d_ws;                // [56][2048] fp16 (224 KB)

    w1_relayout<<<NKT2, 256, 0, stream>>>(W1, WT);
    snn_fused<<<B / 32, 256, 0, stream>>>(x, WT, b1, W2, b2, W3, b3, ns, o);
}